// Round 1
// baseline (2989.360 us; speedup 1.0000x reference)
//
#include <hip/hip_runtime.h>

#define Bn 32
#define Sn 4096
#define Dn 64
#define Hn 128

__device__ __forceinline__ float fsig(float x)  { return 1.0f / (1.0f + __expf(-x)); }
__device__ __forceinline__ float ftanh(float x) { return 2.0f / (1.0f + __expf(-2.0f * x)) - 1.0f; }

// ---------------------------------------------------------------------------
// Kernel 1: sequential GRU recurrence. One block per batch, 256 threads.
//   lanes   0..127 : z-gate for unit j, then h_hat + h update (phase B)
//   lanes 128..255 : r-gate for unit j, write r*h to LDS
// comb  = [ x_t (64) | h_{t-1} (128) ]
// comb2 = [ x_t (64) | r*h     (128) ]
// Weights: only center tap W[:, :, 2] contributes (input len 1, pad 2).
// Group g of output unit j = j>>5 reads channels [48g, 48g+48) of comb.
// ---------------------------------------------------------------------------
__global__ __launch_bounds__(256, 1) void gru_rec(
    const float* __restrict__ x,
    const float* __restrict__ Wz, const float* __restrict__ bz,
    const float* __restrict__ Wr, const float* __restrict__ br,
    const float* __restrict__ Wh, const float* __restrict__ bh,
    float* __restrict__ gout)
{
    __shared__ __align__(16) float comb[192];
    __shared__ __align__(16) float comb2[192];

    const int b = blockIdx.x;
    const int k = threadIdx.x;
    const int j = k & 127;
    const bool zlane = (k < 128);
    const int base = (j >> 5) * 48;

    // load per-unit weights (center tap) into registers
    float w[48], wh[48];
    const float* Wg = zlane ? Wz : Wr;
    #pragma unroll
    for (int c = 0; c < 48; ++c) w[c] = Wg[j * 240 + 5 * c + 2];
    #pragma unroll
    for (int c = 0; c < 48; ++c) wh[c] = Wh[j * 240 + 5 * c + 2];
    const float bgate = zlane ? bz[j] : br[j];
    const float bhat  = bh[j];

    const float* xb = x + (size_t)b * Sn * Dn;
    float* gb = gout + (size_t)b * Sn * Hn;

    // init: x(0) into both x-slots, h = 0
    if (k < 16) {
        float4 v = reinterpret_cast<const float4*>(xb)[k];
        reinterpret_cast<float4*>(comb)[k]  = v;
        reinterpret_cast<float4*>(comb2)[k] = v;
    }
    if (k < 128) comb[64 + k] = 0.0f;
    __syncthreads();

    float4 xn = make_float4(0.f, 0.f, 0.f, 0.f);

    for (int t = 0; t < Sn; ++t) {
        // ---- phase A: z and r gates ----
        if (!zlane) {
            // lanes 128..143: prefetch x(t+1) into registers (written to LDS in phase B)
            if (k < 144 && t + 1 < Sn)
                xn = reinterpret_cast<const float4*>(xb + (size_t)(t + 1) * Dn)[k - 128];
            // lanes 240..255: comb2 x-part <- comb x-part (= x_t, written last phase B)
            if (k >= 240)
                reinterpret_cast<float4*>(comb2)[k - 240] =
                    reinterpret_cast<float4*>(comb)[k - 240];
        }
        const float hj = comb[64 + j];  // h_{t-1}[j]
        float acc = bgate;
        #pragma unroll
        for (int q = 0; q < 12; ++q) {
            float4 v = reinterpret_cast<const float4*>(comb + base)[q];
            acc = fmaf(w[4 * q + 0], v.x, acc);
            acc = fmaf(w[4 * q + 1], v.y, acc);
            acc = fmaf(w[4 * q + 2], v.z, acc);
            acc = fmaf(w[4 * q + 3], v.w, acc);
        }
        const float gate = fsig(acc);
        if (!zlane) comb2[64 + j] = gate * hj;   // r * h
        __syncthreads();

        // ---- phase B: h_hat and state update ----
        if (zlane) {
            float acc2 = bhat;
            #pragma unroll
            for (int q = 0; q < 12; ++q) {
                float4 v = reinterpret_cast<const float4*>(comb2 + base)[q];
                acc2 = fmaf(wh[4 * q + 0], v.x, acc2);
                acc2 = fmaf(wh[4 * q + 1], v.y, acc2);
                acc2 = fmaf(wh[4 * q + 2], v.z, acc2);
                acc2 = fmaf(wh[4 * q + 3], v.w, acc2);
            }
            const float hh = ftanh(acc2);
            const float hnew = (1.0f - gate) * hj + gate * hh;
            comb[64 + j] = hnew;
            gb[(size_t)t * Hn + j] = hnew;
        } else if (k < 144) {
            if (t + 1 < Sn)
                reinterpret_cast<float4*>(comb)[k - 128] = xn;  // x(t+1) into comb
        }
        __syncthreads();
    }
}

// ---------------------------------------------------------------------------
// Kernel 2: scores[b,t] = tanh(g . W1 + b1) . W2 + b2
// 1024 blocks x 256 threads; each wave handles 32 rows; W1 staged in LDS.
// ---------------------------------------------------------------------------
__global__ __launch_bounds__(256) void score_k(
    const float* __restrict__ g, const float* __restrict__ W1,
    const float* __restrict__ b1, const float* __restrict__ W2,
    const float* __restrict__ b2, float* __restrict__ scores)
{
    __shared__ float w1[128 * 128];  // [c][j], j fastest (as stored)
    for (int i = threadIdx.x; i < 128 * 128; i += 256) w1[i] = W1[i];
    __syncthreads();

    const int wave = threadIdx.x >> 6, lane = threadIdx.x & 63;
    const float b1a = b1[lane], b1b = b1[lane + 64];
    const float w2a = W2[lane], w2b = W2[lane + 64];
    const float b2v = b2[0];

    const int rowBase = blockIdx.x * 128 + wave * 32;
    for (int i = 0; i < 32; ++i) {
        const int row = rowBase + i;
        float2 g2 = reinterpret_cast<const float2*>(g + (size_t)row * 128)[lane];
        float y1 = b1a, y2 = b1b;
        #pragma unroll 8
        for (int c2 = 0; c2 < 64; ++c2) {
            float va = __shfl(g2.x, c2, 64);
            float vb = __shfl(g2.y, c2, 64);
            y1 = fmaf(va, w1[(2 * c2) * 128 + lane], y1);
            y1 = fmaf(vb, w1[(2 * c2 + 1) * 128 + lane], y1);
            y2 = fmaf(va, w1[(2 * c2) * 128 + lane + 64], y2);
            y2 = fmaf(vb, w1[(2 * c2 + 1) * 128 + lane + 64], y2);
        }
        float v = ftanh(y1) * w2a + ftanh(y2) * w2b;
        #pragma unroll
        for (int off = 32; off > 0; off >>= 1) v += __shfl_xor(v, off, 64);
        if (lane == 0) scores[row] = v + b2v;
    }
}

// ---------------------------------------------------------------------------
// Kernel 3: per-batch softmax max & sum-exp
// ---------------------------------------------------------------------------
__global__ __launch_bounds__(256) void smax_k(const float* __restrict__ scores,
                                              float* __restrict__ ml)
{
    __shared__ float red[256];
    const int b = blockIdx.x, tid = threadIdx.x;
    const float* sc = scores + (size_t)b * Sn;
    float m = -3.4e38f;
    for (int i = tid; i < Sn; i += 256) m = fmaxf(m, sc[i]);
    red[tid] = m;
    __syncthreads();
    for (int s = 128; s > 0; s >>= 1) {
        if (tid < s) red[tid] = fmaxf(red[tid], red[tid + s]);
        __syncthreads();
    }
    m = red[0];
    __syncthreads();
    float l = 0.f;
    for (int i = tid; i < Sn; i += 256) l += __expf(sc[i] - m);
    red[tid] = l;
    __syncthreads();
    for (int s = 128; s > 0; s >>= 1) {
        if (tid < s) red[tid] += red[tid + s];
        __syncthreads();
    }
    if (tid == 0) { ml[2 * b] = m; ml[2 * b + 1] = red[0]; }
}

// ---------------------------------------------------------------------------
// Kernel 4: partial weighted sums over t-chunks of 256
// ---------------------------------------------------------------------------
__global__ __launch_bounds__(256) void ctx_part_k(
    const float* __restrict__ g, const float* __restrict__ scores,
    const float* __restrict__ ml, float* __restrict__ part)
{
    const int b = blockIdx.x >> 4, chunk = blockIdx.x & 15;
    const int tid = threadIdx.x, j = tid & 127, half = tid >> 7;
    const float m = ml[2 * b], linv = 1.0f / ml[2 * b + 1];
    const float* gp = g + ((size_t)b * Sn + chunk * 256) * Hn;
    const float* sp = scores + (size_t)b * Sn + chunk * 256;
    float acc = 0.f;
    for (int i = half; i < 256; i += 2)
        acc = fmaf(__expf(sp[i] - m), gp[(size_t)i * Hn + j], acc);
    __shared__ float tmp[128];
    if (half) tmp[j] = acc;
    __syncthreads();
    if (!half) part[(size_t)blockIdx.x * Hn + j] = (acc + tmp[j]) * linv;
}

// ---------------------------------------------------------------------------
// Kernel 5: reduce chunk partials -> context (B, H)
// ---------------------------------------------------------------------------
__global__ __launch_bounds__(128) void ctx_final_k(const float* __restrict__ part,
                                                   float* __restrict__ out)
{
    const int b = blockIdx.x, j = threadIdx.x;
    float acc = 0.f;
    for (int c = 0; c < 16; ++c) acc += part[(size_t)(b * 16 + c) * Hn + j];
    out[b * Hn + j] = acc;
}

extern "C" void kernel_launch(void* const* d_in, const int* in_sizes, int n_in,
                              void* d_out, int out_size, void* d_ws, size_t ws_size,
                              hipStream_t stream)
{
    const float* x  = (const float*)d_in[0];
    const float* Wz = (const float*)d_in[1];
    const float* bz = (const float*)d_in[2];
    const float* Wr = (const float*)d_in[3];
    const float* br = (const float*)d_in[4];
    const float* Wh = (const float*)d_in[5];
    const float* bh = (const float*)d_in[6];
    const float* W1 = (const float*)d_in[7];
    const float* b1 = (const float*)d_in[8];
    const float* W2 = (const float*)d_in[9];
    const float* b2 = (const float*)d_in[10];
    float* out = (float*)d_out;

    // workspace layout (bytes):
    //   g       : 32*4096*128*4 = 67108864
    //   scores  : 32*4096*4     = 524288
    //   ml      : 64*4          = 256
    //   part    : 32*16*128*4   = 262144
    char* ws = (char*)d_ws;
    float* g      = (float*)(ws);
    float* scores = (float*)(ws + 67108864);
    float* ml     = (float*)(ws + 67108864 + 524288);
    float* part   = (float*)(ws + 67108864 + 524288 + 256);

    gru_rec<<<32, 256, 0, stream>>>(x, Wz, bz, Wr, br, Wh, bh, g);
    score_k<<<1024, 256, 0, stream>>>(g, W1, b1, W2, b2, scores);
    smax_k<<<32, 256, 0, stream>>>(scores, ml);
    ctx_part_k<<<512, 256, 0, stream>>>(g, scores, ml, part);
    ctx_final_k<<<32, 128, 0, stream>>>(part, out);
}